// Round 4
// baseline (561.187 us; speedup 1.0000x reference)
//
#include <hip/hip_runtime.h>
#include <hip/hip_bf16.h>

#define VOCAB 30522
#define VPAD 30592   // VOCAB padded to multiple of 128 (for branch-free B staging)
#define HIDDEN 768
#define NHEADS 4
#define NHID 128
#define ROWS 2048
#define KDIM 512
#define LN_EPS 1e-12f
#define ALPHA_LR 0.01f
#define NEGV -9.0e15f
#define NTILE 239   // ceil(30522/128)
#define NT2 480     // padded partial count (2*NTILE=478, pad to 480)

typedef __attribute__((ext_vector_type(8))) short short8;
typedef __attribute__((ext_vector_type(4))) float floatx4;
typedef __attribute__((ext_vector_type(2))) float floatx2;
typedef __attribute__((ext_vector_type(4))) unsigned short ushort4v;

static __device__ __forceinline__ unsigned short f2bf(float f) {
  unsigned int u = __float_as_uint(f);
  unsigned int r = u + 0x7fffu + ((u >> 16) & 1u);
  return (unsigned short)(r >> 16);
}

// async global->LDS, 16B per lane (dest must be wave-linear: base + lane*16)
static __device__ __forceinline__ void gload16(const unsigned short* g, unsigned short* l) {
  __builtin_amdgcn_global_load_lds(
      (const __attribute__((address_space(1))) void*)g,
      (__attribute__((address_space(3))) void*)l, 16, 0, 0);
}

// ---------------- kernel 0: out_W fp32 -> bf16 (+ zero pad rows) ----------------
__global__ __launch_bounds__(256) void k_convert(const float* __restrict__ src,
                                                 unsigned short* __restrict__ dst,
                                                 int n4src, int n4tot) {
  int i = blockIdx.x * blockDim.x + threadIdx.x;
  int stride = gridDim.x * blockDim.x;
  for (; i < n4tot; i += stride) {
    ushort4v o = {0, 0, 0, 0};
    if (i < n4src) {
      floatx4 v = reinterpret_cast<const floatx4*>(src)[i];
      o.x = f2bf(v.x); o.y = f2bf(v.y); o.z = f2bf(v.z); o.w = f2bf(v.w);
    }
    reinterpret_cast<ushort4v*>(dst)[i] = o;
  }
}

// ---------------- kernel 1: embeddings + LayerNorm ----------------
__global__ __launch_bounds__(256) void k_embed_ln(const int* __restrict__ tok, const int* __restrict__ typ,
    const float* __restrict__ tok_emb, const float* __restrict__ type_emb, const float* __restrict__ pos_emb,
    const float* __restrict__ ln_g, const float* __restrict__ ln_b, float* __restrict__ xout) {
  int row = blockIdx.x;
  int n = row & 255;
  int t = tok[row], ty = typ[row];
  const float* te = tok_emb + (long)t * HIDDEN;
  const float* ye = type_emb + (long)ty * HIDDEN;
  const float* pe = pos_emb + (long)n * HIDDEN;
  float v[3]; float s = 0.f, ss = 0.f;
  #pragma unroll
  for (int q = 0; q < 3; q++) {
    int d = threadIdx.x + q * 256;
    float x = te[d] + ye[d] + pe[d];
    v[q] = x; s += x; ss += x * x;
  }
  __shared__ float red[8];
  for (int off = 32; off; off >>= 1) { s += __shfl_down(s, off); ss += __shfl_down(ss, off); }
  int wid = threadIdx.x >> 6;
  if ((threadIdx.x & 63) == 0) { red[wid] = s; red[4 + wid] = ss; }
  __syncthreads();
  if (threadIdx.x == 0) {
    float a = red[0] + red[1] + red[2] + red[3];
    float b = red[4] + red[5] + red[6] + red[7];
    float mu = a * (1.0f / 768.0f);
    float var = b * (1.0f / 768.0f) - mu * mu;
    red[0] = mu; red[1] = rsqrtf(var + LN_EPS);
  }
  __syncthreads();
  float mu = red[0], rstd = red[1];
  #pragma unroll
  for (int q = 0; q < 3; q++) {
    int d = threadIdx.x + q * 256;
    xout[(long)row * HIDDEN + d] = (v[q] - mu) * rstd * ln_g[d] + ln_b[d];
  }
}

// ---------------- kernel 2: Wh = x @ W (fp32 tiled GEMM) ----------------
__global__ __launch_bounds__(256) void k_wh(const float* __restrict__ x, const float* __restrict__ W,
                                            float* __restrict__ Wh) {
  int bm = blockIdx.x & 31, bn = blockIdx.x >> 5;   // 32 x 8
  int m0 = bm * 64, n0 = bn * 64;
  __shared__ float As[16][65];
  __shared__ float Bs[16][64];
  int tx = threadIdx.x & 15, ty = threadIdx.x >> 4;
  float acc[4][4] = {};
  for (int k0 = 0; k0 < HIDDEN; k0 += 16) {
    #pragma unroll
    for (int q = 0; q < 4; q++) {
      int e = threadIdx.x + q * 256;
      int m = e >> 4, k = e & 15;
      As[k][m] = x[(long)(m0 + m) * HIDDEN + k0 + k];
    }
    #pragma unroll
    for (int q = 0; q < 4; q++) {
      int e = threadIdx.x + q * 256;
      int nn = e & 63, k = e >> 6;
      int c = n0 + nn;
      Bs[k][nn] = W[((long)(c >> 7) * HIDDEN + (k0 + k)) * NHID + (c & 127)];
    }
    __syncthreads();
    #pragma unroll
    for (int k = 0; k < 16; k++) {
      float av[4], bv[4];
      #pragma unroll
      for (int i = 0; i < 4; i++) av[i] = As[k][ty * 4 + i];
      #pragma unroll
      for (int j = 0; j < 4; j++) bv[j] = Bs[k][tx * 4 + j];
      #pragma unroll
      for (int i = 0; i < 4; i++)
        #pragma unroll
        for (int j = 0; j < 4; j++) acc[i][j] += av[i] * bv[j];
    }
    __syncthreads();
  }
  #pragma unroll
  for (int i = 0; i < 4; i++)
    #pragma unroll
    for (int j = 0; j < 4; j++) {
      int row = m0 + ty * 4 + i, c = n0 + tx * 4 + j;
      Wh[((long)(c >> 7) * ROWS + row) * NHID + (c & 127)] = acc[i][j];
    }
}

// ---------------- kernel 3: e1/e2 = Wh . a1/a2 ----------------
__global__ __launch_bounds__(256) void k_e12(const float* __restrict__ Wh, const float* __restrict__ a,
                                             float* __restrict__ e1, float* __restrict__ e2) {
  int h = blockIdx.x >> 3, b = blockIdx.x & 7;
  __shared__ float av[256];
  av[threadIdx.x] = a[h * 256 + threadIdx.x];
  __syncthreads();
  int row = b * 256 + threadIdx.x;
  const float* wr = Wh + ((long)h * ROWS + row) * NHID;
  float s1 = 0.f, s2 = 0.f;
  #pragma unroll 8
  for (int f = 0; f < 128; f++) { float w = wr[f]; s1 += w * av[f]; s2 += w * av[128 + f]; }
  e1[h * ROWS + row] = s1; e2[h * ROWS + row] = s2;
}

__device__ __forceinline__ unsigned char mk_flags(int t, int hwv, int tokv) {
  unsigned char fl = 0;
  if (hwv) {
    if (t == 1) fl |= 1;
    if (t == 3) fl |= 2;
    if (t == 0 || t == 2 || t == 5) fl |= 4;
    if (t == 6 || t == 4 || t == 0) fl |= 8;
  }
  if (tokv != 0) fl |= 16;
  return fl;
}

// ---------------- kernel 4a: column-wise softmax stats ----------------
__global__ __launch_bounds__(256) void k_colstats(const int* __restrict__ tok, const int* __restrict__ typ,
    const int* __restrict__ syn, const int* __restrict__ hw,
    const float* __restrict__ e1, const float* __restrict__ e2,
    float* __restrict__ colmax, float* __restrict__ colrs) {
  int h = blockIdx.x >> 3, b = blockIdx.x & 7;
  __shared__ float E1[256]; __shared__ int SY[256]; __shared__ unsigned char FL[256];
  int tid = threadIdx.x;
  int g = b * 256 + tid;
  FL[tid] = mk_flags(typ[g], hw[g], tok[g]);
  E1[tid] = e1[h * ROWS + g];
  SY[tid] = syn[g];
  __syncthreads();
  float e2j = e2[h * ROWS + g];
  int syj = SY[tid]; unsigned char flj = FL[tid];
  bool npj = flj & 16, d1j = flj & 4, d3j = flj & 8;
  float m = -INFINITY;
  for (int i = 0; i < 256; i++) {
    float e = E1[i] + e2j;
    e = e > 0.f ? e : ALPHA_LR * e;
    unsigned char fli = FL[i];
    bool vis = (SY[i] == syj) || ((fli & 1) && d1j) || ((fli & 2) && d3j);
    float v = (vis && npj) ? e : NEGV;
    m = fmaxf(m, v);
  }
  float s = 0.f;
  for (int i = 0; i < 256; i++) {
    float e = E1[i] + e2j;
    e = e > 0.f ? e : ALPHA_LR * e;
    unsigned char fli = FL[i];
    bool vis = (SY[i] == syj) || ((fli & 1) && d1j) || ((fli & 2) && d3j);
    float v = (vis && npj) ? e : NEGV;
    s += __expf(v - m);
  }
  int idx = (h * 8 + b) * 256 + tid;
  colmax[idx] = m;
  colrs[idx] = 1.0f / s;
}

// ---------------- kernel 4b: hp = elu(att @ Wh) -> cat (bf16) ----------------
__global__ __launch_bounds__(256) void k_att(const int* __restrict__ tok, const int* __restrict__ typ,
    const int* __restrict__ syn, const int* __restrict__ hw,
    const float* __restrict__ e1, const float* __restrict__ e2,
    const float* __restrict__ colmax, const float* __restrict__ colrs,
    const float* __restrict__ Wh, unsigned short* __restrict__ cat) {
  int chunk = blockIdx.x & 3; int hb = blockIdx.x >> 2;
  int h = hb >> 3, b = hb & 7;
  __shared__ float E2[256], CM[256], CR[256];
  __shared__ int SY[256]; __shared__ unsigned char FL[256];
  __shared__ float WJ[64][128];
  int tid = threadIdx.x;
  {
    int g = b * 256 + tid;
    FL[tid] = mk_flags(typ[g], hw[g], tok[g]);
    E2[tid] = e2[h * ROWS + g];
    CM[tid] = colmax[hb * 256 + tid];
    CR[tid] = colrs[hb * 256 + tid];
    SY[tid] = syn[g];
  }
  __syncthreads();
  int i = chunk * 64 + (tid >> 2);
  int gi = b * 256 + i;
  float e1i = e1[h * ROWS + gi];
  unsigned char fli = FL[i];
  bool s1i = fli & 1, s3i = fli & 2;
  int syni = SY[i];
  int f0 = tid & 3;
  float acc[32] = {};
  for (int j0 = 0; j0 < 256; j0 += 64) {
    #pragma unroll
    for (int q = 0; q < 32; q++) {
      int e = tid + q * 256;
      int j = e >> 7, f = e & 127;
      WJ[j][f] = Wh[((long)h * ROWS + b * 256 + j0 + j) * NHID + f];
    }
    __syncthreads();
    for (int j = 0; j < 64; j++) {
      int jj = j0 + j;
      unsigned char flj = FL[jj];
      bool vis = (syni == SY[jj]) || (s1i && (flj & 4)) || (s3i && (flj & 8));
      bool msk = vis && (flj & 16);
      float ev = e1i + E2[jj];
      ev = ev > 0.f ? ev : ALPHA_LR * ev;
      float v = msk ? ev : NEGV;
      float w = __expf(v - CM[jj]) * CR[jj];
      #pragma unroll
      for (int k = 0; k < 32; k++) acc[k] += w * WJ[j][f0 + 4 * k];
    }
    __syncthreads();
  }
  unsigned short* cr = cat + (long)gi * KDIM + h * NHID;
  #pragma unroll
  for (int k = 0; k < 32; k++) {
    float v = acc[k];
    v = v > 0.f ? v : __expf(v) - 1.f;
    cr[f0 + 4 * k] = f2bf(v);
  }
}

// ---------------- kernel 5: big GEMM (bf16 MFMA, dbuf + both-sides swizzle) ----------------
// C(2048 x 30522) = cat(2048x512) @ owb(VPAD x 512)^T ; elu+bias fused; partial sumexp per (row, 64-col tile)
__global__ __launch_bounds__(256) void k_gemm(const unsigned short* __restrict__ A,
    const unsigned short* __restrict__ Bw, const float* __restrict__ bias,
    float* __restrict__ out, float* __restrict__ ps) {
  // bijective XCD swizzle: 3824 blocks, 3824 % 8 == 0
  int bid = blockIdx.x;
  bid = (bid & 7) * ((16 * NTILE) >> 3) + (bid >> 3);
  int mt = bid & 15, nt = bid >> 4;
  int m0 = mt * 128, n0 = nt * 128;
  __shared__ __align__(16) unsigned short Al[2][128 * 64];
  __shared__ __align__(16) unsigned short Bl[2][128 * 64];
  int tid = threadIdx.x;
  int l = tid & 63, wid = tid >> 6;
  int wr = wid >> 1, wc = wid & 1;
  int lrow = l & 15, lgrp = l >> 4;
  floatx4 zero = {0.f, 0.f, 0.f, 0.f};
  floatx4 acc[4][4];
  #pragma unroll
  for (int i = 0; i < 4; i++)
    #pragma unroll
    for (int j = 0; j < 4; j++) acc[i][j] = zero;
  const unsigned short* Ab = A + (long)m0 * KDIM;
  const unsigned short* Bb = Bw + (long)n0 * KDIM;
  // per-lane staging source offset (swizzled slot within 64-elem k-segment)
  // chunk = q*256+tid; row=chunk>>3; kp=chunk&7; src slot = kp^(row&7)
  // prologue: stage kt=0 into buf 0
  #pragma unroll
  for (int q = 0; q < 4; q++) {
    int chunk = q * 256 + tid;
    int row = chunk >> 3, kp = chunk & 7, swz = kp ^ (row & 7);
    long off = (long)row * KDIM + swz * 8;
    gload16(Ab + off, &Al[0][chunk * 8]);
    gload16(Bb + off, &Bl[0][chunk * 8]);
  }
  __syncthreads();
  for (int kt = 0; kt < 8; kt++) {
    int cur = kt & 1;
    if (kt < 7) {
      #pragma unroll
      for (int q = 0; q < 4; q++) {
        int chunk = q * 256 + tid;
        int row = chunk >> 3, kp = chunk & 7, swz = kp ^ (row & 7);
        long off = (long)row * KDIM + (kt + 1) * 64 + swz * 8;
        gload16(Ab + off, &Al[cur ^ 1][chunk * 8]);
        gload16(Bb + off, &Bl[cur ^ 1][chunk * 8]);
      }
    }
    #pragma unroll
    for (int kk = 0; kk < 2; kk++) {
      int sA = (kk * 4 + lgrp) ^ (lrow & 7);   // swizzled 16B slot
      short8 af[4], bf[4];
      #pragma unroll
      for (int mi = 0; mi < 4; mi++)
        af[mi] = *reinterpret_cast<const short8*>(&Al[cur][(wr * 64 + mi * 16 + lrow) * 64 + sA * 8]);
      #pragma unroll
      for (int ni = 0; ni < 4; ni++)
        bf[ni] = *reinterpret_cast<const short8*>(&Bl[cur][(wc * 64 + ni * 16 + lrow) * 64 + sA * 8]);
      #pragma unroll
      for (int mi = 0; mi < 4; mi++)
        #pragma unroll
        for (int ni = 0; ni < 4; ni++)
          acc[mi][ni] = __builtin_amdgcn_mfma_f32_16x16x32_bf16(af[mi], bf[ni], acc[mi][ni], 0, 0, 0);
    }
    __syncthreads();
  }
  // epilogue: bias + elu + store + per-row partial sum of exp (no max: logits are small)
  int t2 = nt * 2 + wc;
  float bcol[4]; bool valid[4]; int cols[4];
  #pragma unroll
  for (int ni = 0; ni < 4; ni++) {
    int c = n0 + wc * 64 + ni * 16 + lrow;
    cols[ni] = c; valid[ni] = c < VOCAB;
    bcol[ni] = valid[ni] ? bias[c] : 0.f;
  }
  #pragma unroll
  for (int mi = 0; mi < 4; mi++) {
    #pragma unroll
    for (int reg = 0; reg < 4; reg++) {
      int row = m0 + wr * 64 + mi * 16 + lgrp * 4 + reg;
      float se = 0.f;
      #pragma unroll
      for (int ni = 0; ni < 4; ni++) {
        float z = acc[mi][ni][reg] + bcol[ni];
        float o = z > 0.f ? z : __expf(z) - 1.f;
        if (valid[ni]) {
          out[(long)row * VOCAB + cols[ni]] = o;
          se += __expf(o);
        }
      }
      #pragma unroll
      for (int off = 1; off < 16; off <<= 1) se += __shfl_xor(se, off);
      if (lrow == 0) ps[(long)row * NT2 + t2] = se;
    }
  }
}

// ---------------- kernel 6: reduce partial sumexp -> lse per row ----------------
__global__ __launch_bounds__(256) void k_lse(const float* __restrict__ ps, float* __restrict__ lse) {
  int row = blockIdx.x;
  int tid = threadIdx.x;
  const float* psr = ps + (long)row * NT2;
  float s = (tid < 478 ? psr[tid] : 0.f) + (tid + 256 < 478 ? psr[tid + 256] : 0.f);
  #pragma unroll
  for (int off = 32; off; off >>= 1) s += __shfl_xor(s, off);
  __shared__ float red[4];
  int wid = tid >> 6;
  if ((tid & 63) == 0) red[wid] = s;
  __syncthreads();
  if (tid == 0) lse[row] = logf(red[0] + red[1] + red[2] + red[3]);
}

// ---------------- kernel 7: out -= lse[row] (2D grid, no divisions) ----------------
__global__ __launch_bounds__(256) void k_sub(float* __restrict__ out, const float* __restrict__ lse) {
  int row = blockIdx.y;
  float L = lse[row];
  floatx2* o = reinterpret_cast<floatx2*>(out + (long)row * VOCAB);
  int base = blockIdx.x * 1024 + threadIdx.x;
  #pragma unroll
  for (int k = 0; k < 4; k++) {
    int c2 = base + k * 256;
    if (c2 < VOCAB / 2) {
      floatx2 v = o[c2];
      v.x -= L; v.y -= L;
      o[c2] = v;
    }
  }
}

extern "C" void kernel_launch(void* const* d_in, const int* in_sizes, int n_in,
                              void* d_out, int out_size, void* d_ws, size_t ws_size,
                              hipStream_t stream) {
  const int* tok = (const int*)d_in[0];
  const int* typ = (const int*)d_in[1];
  const int* syn = (const int*)d_in[2];
  const int* hw  = (const int*)d_in[3];
  const float* tok_emb  = (const float*)d_in[4];
  const float* type_emb = (const float*)d_in[5];
  const float* pos_emb  = (const float*)d_in[6];
  const float* ln_g = (const float*)d_in[7];
  const float* ln_b = (const float*)d_in[8];
  const float* W    = (const float*)d_in[9];
  const float* a    = (const float*)d_in[10];
  const float* out_W = (const float*)d_in[11];
  const float* out_b = (const float*)d_in[12];
  float* out = (float*)d_out;
  char* ws = (char*)d_ws;
  // ws layout (bytes)
  float* x   = (float*)(ws + 0);                 // 2048*768*4   = 6291456
  float* Wh  = (float*)(ws + 6291456);           // 4*2048*128*4 = 4194304
  float* e1  = (float*)(ws + 10485760);          // 32768
  float* e2  = (float*)(ws + 10518528);          // 32768
  float* cm  = (float*)(ws + 10551296);          // 32768
  float* cs  = (float*)(ws + 10584064);          // 32768
  unsigned short* cat = (unsigned short*)(ws + 10616832);  // 2048*512*2 = 2097152
  unsigned short* owb = (unsigned short*)(ws + 12713984);  // VPAD*512*2 = 31326208
  float* ps  = (float*)(ws + 44040192);          // 2048*480*4 = 3932160
  float* lse = (float*)(ws + 47972352);          // 8192

  k_convert<<<2048, 256, 0, stream>>>(out_W, owb, (VOCAB * KDIM) / 4, (VPAD * KDIM) / 4);
  k_embed_ln<<<2048, 256, 0, stream>>>(tok, typ, tok_emb, type_emb, pos_emb, ln_g, ln_b, x);
  k_wh<<<256, 256, 0, stream>>>(x, W, Wh);
  k_e12<<<32, 256, 0, stream>>>(Wh, a, e1, e2);
  k_colstats<<<32, 256, 0, stream>>>(tok, typ, syn, hw, e1, e2, cm, cs);
  k_att<<<128, 256, 0, stream>>>(tok, typ, syn, hw, e1, e2, cm, cs, Wh, cat);
  k_gemm<<<16 * NTILE, 256, 0, stream>>>(cat, owb, out_b, out, ps);
  k_lse<<<2048, 256, 0, stream>>>(ps, lse);
  k_sub<<<dim3(15, 2048), 256, 0, stream>>>(out, lse);
}

// Round 5
// 447.339 us; speedup vs baseline: 1.2545x; 1.2545x over previous
//
#include <hip/hip_runtime.h>
#include <hip/hip_bf16.h>

#define VOCAB 30522
#define VPAD 30592   // VOCAB padded to multiple of 128 (for branch-free B staging)
#define HIDDEN 768
#define NHEADS 4
#define NHID 128
#define ROWS 2048
#define KDIM 512
#define LN_EPS 1e-12f
#define ALPHA_LR 0.01f
#define NEGV -9.0e15f
#define NTILE 239   // ceil(30522/128)
#define NT2 480     // padded partial count (2*NTILE=478, pad to 480)

typedef __attribute__((ext_vector_type(8))) short short8;
typedef __attribute__((ext_vector_type(4))) float floatx4;
typedef __attribute__((ext_vector_type(2))) float floatx2;
typedef __attribute__((ext_vector_type(4))) unsigned short ushort4v;

static __device__ __forceinline__ unsigned short f2bf(float f) {
  unsigned int u = __float_as_uint(f);
  unsigned int r = u + 0x7fffu + ((u >> 16) & 1u);
  return (unsigned short)(r >> 16);
}

// async global->LDS, 16B per lane (dest must be wave-linear: base + lane*16)
static __device__ __forceinline__ void gload16(const unsigned short* g, unsigned short* l) {
  __builtin_amdgcn_global_load_lds(
      (const __attribute__((address_space(1))) void*)g,
      (__attribute__((address_space(3))) void*)l, 16, 0, 0);
}

// ---------------- kernel 0: out_W fp32 -> bf16 (+ zero pad rows) ----------------
__global__ __launch_bounds__(256) void k_convert(const float* __restrict__ src,
                                                 unsigned short* __restrict__ dst,
                                                 int n4src, int n4tot) {
  int i = blockIdx.x * blockDim.x + threadIdx.x;
  int stride = gridDim.x * blockDim.x;
  for (; i < n4tot; i += stride) {
    ushort4v o = {0, 0, 0, 0};
    if (i < n4src) {
      floatx4 v = reinterpret_cast<const floatx4*>(src)[i];
      o.x = f2bf(v.x); o.y = f2bf(v.y); o.z = f2bf(v.z); o.w = f2bf(v.w);
    }
    reinterpret_cast<ushort4v*>(dst)[i] = o;
  }
}

// ---------------- kernel 1: embeddings + LayerNorm ----------------
__global__ __launch_bounds__(256) void k_embed_ln(const int* __restrict__ tok, const int* __restrict__ typ,
    const float* __restrict__ tok_emb, const float* __restrict__ type_emb, const float* __restrict__ pos_emb,
    const float* __restrict__ ln_g, const float* __restrict__ ln_b, float* __restrict__ xout) {
  int row = blockIdx.x;
  int n = row & 255;
  int t = tok[row], ty = typ[row];
  const float* te = tok_emb + (long)t * HIDDEN;
  const float* ye = type_emb + (long)ty * HIDDEN;
  const float* pe = pos_emb + (long)n * HIDDEN;
  float v[3]; float s = 0.f, ss = 0.f;
  #pragma unroll
  for (int q = 0; q < 3; q++) {
    int d = threadIdx.x + q * 256;
    float x = te[d] + ye[d] + pe[d];
    v[q] = x; s += x; ss += x * x;
  }
  __shared__ float red[8];
  for (int off = 32; off; off >>= 1) { s += __shfl_down(s, off); ss += __shfl_down(ss, off); }
  int wid = threadIdx.x >> 6;
  if ((threadIdx.x & 63) == 0) { red[wid] = s; red[4 + wid] = ss; }
  __syncthreads();
  if (threadIdx.x == 0) {
    float a = red[0] + red[1] + red[2] + red[3];
    float b = red[4] + red[5] + red[6] + red[7];
    float mu = a * (1.0f / 768.0f);
    float var = b * (1.0f / 768.0f) - mu * mu;
    red[0] = mu; red[1] = rsqrtf(var + LN_EPS);
  }
  __syncthreads();
  float mu = red[0], rstd = red[1];
  #pragma unroll
  for (int q = 0; q < 3; q++) {
    int d = threadIdx.x + q * 256;
    xout[(long)row * HIDDEN + d] = (v[q] - mu) * rstd * ln_g[d] + ln_b[d];
  }
}

// ---------------- kernel 2: Wh = x @ W (fp32 tiled GEMM) ----------------
__global__ __launch_bounds__(256) void k_wh(const float* __restrict__ x, const float* __restrict__ W,
                                            float* __restrict__ Wh) {
  int bm = blockIdx.x & 31, bn = blockIdx.x >> 5;   // 32 x 8
  int m0 = bm * 64, n0 = bn * 64;
  __shared__ float As[16][65];
  __shared__ float Bs[16][64];
  int tx = threadIdx.x & 15, ty = threadIdx.x >> 4;
  float acc[4][4] = {};
  for (int k0 = 0; k0 < HIDDEN; k0 += 16) {
    #pragma unroll
    for (int q = 0; q < 4; q++) {
      int e = threadIdx.x + q * 256;
      int m = e >> 4, k = e & 15;
      As[k][m] = x[(long)(m0 + m) * HIDDEN + k0 + k];
    }
    #pragma unroll
    for (int q = 0; q < 4; q++) {
      int e = threadIdx.x + q * 256;
      int nn = e & 63, k = e >> 6;
      int c = n0 + nn;
      Bs[k][nn] = W[((long)(c >> 7) * HIDDEN + (k0 + k)) * NHID + (c & 127)];
    }
    __syncthreads();
    #pragma unroll
    for (int k = 0; k < 16; k++) {
      float av[4], bv[4];
      #pragma unroll
      for (int i = 0; i < 4; i++) av[i] = As[k][ty * 4 + i];
      #pragma unroll
      for (int j = 0; j < 4; j++) bv[j] = Bs[k][tx * 4 + j];
      #pragma unroll
      for (int i = 0; i < 4; i++)
        #pragma unroll
        for (int j = 0; j < 4; j++) acc[i][j] += av[i] * bv[j];
    }
    __syncthreads();
  }
  #pragma unroll
  for (int i = 0; i < 4; i++)
    #pragma unroll
    for (int j = 0; j < 4; j++) {
      int row = m0 + ty * 4 + i, c = n0 + tx * 4 + j;
      Wh[((long)(c >> 7) * ROWS + row) * NHID + (c & 127)] = acc[i][j];
    }
}

// ---------------- kernel 3: e1/e2 = Wh . a1/a2 ----------------
__global__ __launch_bounds__(256) void k_e12(const float* __restrict__ Wh, const float* __restrict__ a,
                                             float* __restrict__ e1, float* __restrict__ e2) {
  int h = blockIdx.x >> 3, b = blockIdx.x & 7;
  __shared__ float av[256];
  av[threadIdx.x] = a[h * 256 + threadIdx.x];
  __syncthreads();
  int row = b * 256 + threadIdx.x;
  const float* wr = Wh + ((long)h * ROWS + row) * NHID;
  float s1 = 0.f, s2 = 0.f;
  #pragma unroll 8
  for (int f = 0; f < 128; f++) { float w = wr[f]; s1 += w * av[f]; s2 += w * av[128 + f]; }
  e1[h * ROWS + row] = s1; e2[h * ROWS + row] = s2;
}

__device__ __forceinline__ unsigned char mk_flags(int t, int hwv, int tokv) {
  unsigned char fl = 0;
  if (hwv) {
    if (t == 1) fl |= 1;
    if (t == 3) fl |= 2;
    if (t == 0 || t == 2 || t == 5) fl |= 4;
    if (t == 6 || t == 4 || t == 0) fl |= 8;
  }
  if (tokv != 0) fl |= 16;
  return fl;
}

// ---------------- kernel 4a: column-wise softmax stats ----------------
__global__ __launch_bounds__(256) void k_colstats(const int* __restrict__ tok, const int* __restrict__ typ,
    const int* __restrict__ syn, const int* __restrict__ hw,
    const float* __restrict__ e1, const float* __restrict__ e2,
    float* __restrict__ colmax, float* __restrict__ colrs) {
  int h = blockIdx.x >> 3, b = blockIdx.x & 7;
  __shared__ float E1[256]; __shared__ int SY[256]; __shared__ unsigned char FL[256];
  int tid = threadIdx.x;
  int g = b * 256 + tid;
  FL[tid] = mk_flags(typ[g], hw[g], tok[g]);
  E1[tid] = e1[h * ROWS + g];
  SY[tid] = syn[g];
  __syncthreads();
  float e2j = e2[h * ROWS + g];
  int syj = SY[tid]; unsigned char flj = FL[tid];
  bool npj = flj & 16, d1j = flj & 4, d3j = flj & 8;
  float m = -INFINITY;
  for (int i = 0; i < 256; i++) {
    float e = E1[i] + e2j;
    e = e > 0.f ? e : ALPHA_LR * e;
    unsigned char fli = FL[i];
    bool vis = (SY[i] == syj) || ((fli & 1) && d1j) || ((fli & 2) && d3j);
    float v = (vis && npj) ? e : NEGV;
    m = fmaxf(m, v);
  }
  float s = 0.f;
  for (int i = 0; i < 256; i++) {
    float e = E1[i] + e2j;
    e = e > 0.f ? e : ALPHA_LR * e;
    unsigned char fli = FL[i];
    bool vis = (SY[i] == syj) || ((fli & 1) && d1j) || ((fli & 2) && d3j);
    float v = (vis && npj) ? e : NEGV;
    s += __expf(v - m);
  }
  int idx = (h * 8 + b) * 256 + tid;
  colmax[idx] = m;
  colrs[idx] = 1.0f / s;
}

// ---------------- kernel 4b: hp = elu(att @ Wh) -> cat (bf16) ----------------
__global__ __launch_bounds__(256) void k_att(const int* __restrict__ tok, const int* __restrict__ typ,
    const int* __restrict__ syn, const int* __restrict__ hw,
    const float* __restrict__ e1, const float* __restrict__ e2,
    const float* __restrict__ colmax, const float* __restrict__ colrs,
    const float* __restrict__ Wh, unsigned short* __restrict__ cat) {
  int chunk = blockIdx.x & 3; int hb = blockIdx.x >> 2;
  int h = hb >> 3, b = hb & 7;
  __shared__ float E2[256], CM[256], CR[256];
  __shared__ int SY[256]; __shared__ unsigned char FL[256];
  __shared__ float WJ[64][128];
  int tid = threadIdx.x;
  {
    int g = b * 256 + tid;
    FL[tid] = mk_flags(typ[g], hw[g], tok[g]);
    E2[tid] = e2[h * ROWS + g];
    CM[tid] = colmax[hb * 256 + tid];
    CR[tid] = colrs[hb * 256 + tid];
    SY[tid] = syn[g];
  }
  __syncthreads();
  int i = chunk * 64 + (tid >> 2);
  int gi = b * 256 + i;
  float e1i = e1[h * ROWS + gi];
  unsigned char fli = FL[i];
  bool s1i = fli & 1, s3i = fli & 2;
  int syni = SY[i];
  int f0 = tid & 3;
  floatx4 acc4[8];
  #pragma unroll
  for (int k2 = 0; k2 < 8; k2++) acc4[k2] = (floatx4){0.f, 0.f, 0.f, 0.f};
  for (int j0 = 0; j0 < 256; j0 += 64) {
    #pragma unroll
    for (int q = 0; q < 8; q++) {
      int e = tid + q * 256;          // 0..2047
      int j = e >> 5, f4 = e & 31;
      *reinterpret_cast<floatx4*>(&WJ[j][f4 * 4]) =
          *reinterpret_cast<const floatx4*>(&Wh[((long)h * ROWS + b * 256 + j0 + j) * NHID + f4 * 4]);
    }
    __syncthreads();
    for (int j = 0; j < 64; j++) {
      int jj = j0 + j;
      unsigned char flj = FL[jj];
      bool vis = (syni == SY[jj]) || (s1i && (flj & 4)) || (s3i && (flj & 8));
      bool msk = vis && (flj & 16);
      float ev = e1i + E2[jj];
      ev = ev > 0.f ? ev : ALPHA_LR * ev;
      float v = msk ? ev : NEGV;
      float w = __expf(v - CM[jj]) * CR[jj];
      #pragma unroll
      for (int k2 = 0; k2 < 8; k2++) {
        floatx4 wv = *reinterpret_cast<const floatx4*>(&WJ[j][(f0 + 4 * k2) * 4]);
        acc4[k2] += wv * w;
      }
    }
    __syncthreads();
  }
  ushort4v* cr4 = reinterpret_cast<ushort4v*>(cat + (long)gi * KDIM + h * NHID);
  #pragma unroll
  for (int k2 = 0; k2 < 8; k2++) {
    ushort4v o4;
    #pragma unroll
    for (int e = 0; e < 4; e++) {
      float v = acc4[k2][e];
      v = v > 0.f ? v : __expf(v) - 1.f;
      o4[e] = f2bf(v);
    }
    cr4[f0 + 4 * k2] = o4;
  }
}

// ---------------- kernel 5: big GEMM (bf16 MFMA, counted-vmcnt pipeline) ----------------
// C(2048 x 30522) = cat(2048x512) @ owb(VPAD x 512)^T ; elu+bias fused;
// stores bf16 o into the first half of each output row's fp32 slot; partial sumexp per (row, 64-col tile)
__global__ __launch_bounds__(256) void k_gemm(const unsigned short* __restrict__ A,
    const unsigned short* __restrict__ Bw, const float* __restrict__ bias,
    unsigned short* __restrict__ otmp, float* __restrict__ ps) {
  // bijective XCD swizzle: 3824 blocks, 3824 % 8 == 0
  int bid = blockIdx.x;
  bid = (bid & 7) * ((16 * NTILE) >> 3) + (bid >> 3);
  int mt = bid & 15, nt = bid >> 4;
  int m0 = mt * 128, n0 = nt * 128;
  __shared__ __align__(16) unsigned short Al[2][128 * 64];
  __shared__ __align__(16) unsigned short Bl[2][128 * 64];
  int tid = threadIdx.x;
  int l = tid & 63, wid = tid >> 6;
  int wr = wid >> 1, wc = wid & 1;
  int lrow = l & 15, lgrp = l >> 4;
  floatx4 acc[4][4];
  #pragma unroll
  for (int i = 0; i < 4; i++)
    #pragma unroll
    for (int j = 0; j < 4; j++) acc[i][j] = (floatx4){0.f, 0.f, 0.f, 0.f};
  const unsigned short* Ab = A + (long)m0 * KDIM;
  const unsigned short* Bb = Bw + (long)n0 * KDIM;

  // stage tile t into buffer bufi (8 gload16 per thread; source pre-swizzled, dest linear)
  auto STAGE = [&](int t, int bufi) {
    #pragma unroll
    for (int q = 0; q < 4; q++) {
      int chunk = q * 256 + tid;
      int row = chunk >> 3, kp = chunk & 7, swz = kp ^ (row & 7);
      long off = (long)row * KDIM + t * 64 + swz * 8;
      gload16(Ab + off, &Al[bufi][chunk * 8]);
      gload16(Bb + off, &Bl[bufi][chunk * 8]);
    }
  };

  STAGE(0, 0);
  STAGE(1, 1);
  asm volatile("s_waitcnt vmcnt(8)" ::: "memory");   // tile 0 landed; tile 1 in flight
  __builtin_amdgcn_sched_barrier(0);
  __builtin_amdgcn_s_barrier();

  #pragma unroll
  for (int kt = 0; kt < 8; kt++) {
    int cur = kt & 1;
    // read ALL frags of current tile into registers (16 x ds_read_b128, swizzled slots)
    short8 af[2][4], bf[2][4];
    #pragma unroll
    for (int kk = 0; kk < 2; kk++) {
      int sA = (kk * 4 + lgrp) ^ (lrow & 7);
      #pragma unroll
      for (int mi = 0; mi < 4; mi++)
        af[kk][mi] = *reinterpret_cast<const short8*>(&Al[cur][(wr * 64 + mi * 16 + lrow) * 64 + sA * 8]);
      #pragma unroll
      for (int ni = 0; ni < 4; ni++)
        bf[kk][ni] = *reinterpret_cast<const short8*>(&Bl[cur][(wc * 64 + ni * 16 + lrow) * 64 + sA * 8]);
    }
    asm volatile("s_waitcnt lgkmcnt(0)" ::: "memory");  // my reads of buf[cur] complete
    __builtin_amdgcn_sched_barrier(0);
    __builtin_amdgcn_s_barrier();                       // ALL waves done reading buf[cur]
    __builtin_amdgcn_sched_barrier(0);
    if (kt < 6) STAGE(kt + 2, cur);                     // overwrite buf[cur] with tile kt+2
    #pragma unroll
    for (int kk = 0; kk < 2; kk++)
      #pragma unroll
      for (int mi = 0; mi < 4; mi++)
        #pragma unroll
        for (int ni = 0; ni < 4; ni++)
          acc[mi][ni] = __builtin_amdgcn_mfma_f32_16x16x32_bf16(af[kk][mi], bf[kk][ni], acc[mi][ni], 0, 0, 0);
    if (kt < 6) {
      asm volatile("s_waitcnt vmcnt(8)" ::: "memory");  // tile kt+1 landed; kt+2 still in flight
    } else if (kt == 6) {
      asm volatile("s_waitcnt vmcnt(0)" ::: "memory");  // tail: tile 7 landed
    }
    __builtin_amdgcn_sched_barrier(0);
    if (kt < 7) __builtin_amdgcn_s_barrier();
  }

  // epilogue: bias + elu + bf16 store + per-row partial sum of exp (no max: logits are small)
  int t2 = nt * 2 + wc;
  float bcol[4]; bool valid[4]; int cols[4];
  #pragma unroll
  for (int ni = 0; ni < 4; ni++) {
    int c = n0 + wc * 64 + ni * 16 + lrow;
    cols[ni] = c; valid[ni] = c < VOCAB;
    bcol[ni] = valid[ni] ? bias[c] : 0.f;
  }
  #pragma unroll
  for (int mi = 0; mi < 4; mi++) {
    #pragma unroll
    for (int reg = 0; reg < 4; reg++) {
      int row = m0 + wr * 64 + mi * 16 + lgrp * 4 + reg;
      unsigned short* orow = otmp + (long)row * 2 * VOCAB;  // bf16 area = first half of row's fp32 slot
      float se = 0.f;
      #pragma unroll
      for (int ni = 0; ni < 4; ni++) {
        float z = acc[mi][ni][reg] + bcol[ni];
        float o = z > 0.f ? z : __expf(z) - 1.f;
        if (valid[ni]) {
          orow[cols[ni]] = f2bf(o);
          se += __expf(o);
        }
      }
      #pragma unroll
      for (int off = 1; off < 16; off <<= 1) se += __shfl_xor(se, off);
      if (lrow == 0) ps[(long)row * NT2 + t2] = se;
    }
  }
}

// ---------------- kernel 6: reduce partial sumexp -> lse per row ----------------
__global__ __launch_bounds__(256) void k_lse(const float* __restrict__ ps, float* __restrict__ lse) {
  int row = blockIdx.x;
  int tid = threadIdx.x;
  const float* psr = ps + (long)row * NT2;
  float s = (tid < 478 ? psr[tid] : 0.f) + (tid + 256 < 478 ? psr[tid + 256] : 0.f);
  #pragma unroll
  for (int off = 32; off; off >>= 1) s += __shfl_xor(s, off);
  __shared__ float red[4];
  int wid = tid >> 6;
  if ((tid & 63) == 0) red[wid] = s;
  __syncthreads();
  if (tid == 0) lse[row] = logf(red[0] + red[1] + red[2] + red[3]);
}

// ---------------- kernel 7: in-place bf16 -> (fp32 - lse) row expansion ----------------
// one block per row: load the row's packed bf16 (first half of the fp32 slot) into
// registers, barrier, write fp32. Row-local, so no cross-block hazard.
__global__ __launch_bounds__(1024) void k_sub(float* __restrict__ out, const float* __restrict__ lse) {
  int row = blockIdx.x;
  float L = lse[row];
  float* rb = out + (long)row * VOCAB;
  const unsigned int* src = reinterpret_cast<const unsigned int*>(rb);  // bf16 pairs
  int tid = threadIdx.x;
  unsigned int v[15];
  #pragma unroll
  for (int i = 0; i < 15; i++) {
    int p = tid + i * 1024;
    v[i] = (p < VOCAB / 2) ? src[p] : 0u;
  }
  __syncthreads();
  floatx2* dst = reinterpret_cast<floatx2*>(rb);
  #pragma unroll
  for (int i = 0; i < 15; i++) {
    int p = tid + i * 1024;
    if (p < VOCAB / 2) {
      unsigned int u = v[i];
      float lo = __uint_as_float((u & 0xffffu) << 16);
      float hi = __uint_as_float(u & 0xffff0000u);
      floatx2 o; o.x = lo - L; o.y = hi - L;
      dst[p] = o;
    }
  }
}

extern "C" void kernel_launch(void* const* d_in, const int* in_sizes, int n_in,
                              void* d_out, int out_size, void* d_ws, size_t ws_size,
                              hipStream_t stream) {
  const int* tok = (const int*)d_in[0];
  const int* typ = (const int*)d_in[1];
  const int* syn = (const int*)d_in[2];
  const int* hw  = (const int*)d_in[3];
  const float* tok_emb  = (const float*)d_in[4];
  const float* type_emb = (const float*)d_in[5];
  const float* pos_emb  = (const float*)d_in[6];
  const float* ln_g = (const float*)d_in[7];
  const float* ln_b = (const float*)d_in[8];
  const float* W    = (const float*)d_in[9];
  const float* a    = (const float*)d_in[10];
  const float* out_W = (const float*)d_in[11];
  const float* out_b = (const float*)d_in[12];
  float* out = (float*)d_out;
  char* ws = (char*)d_ws;
  // ws layout (bytes)
  float* x   = (float*)(ws + 0);                 // 2048*768*4   = 6291456
  float* Wh  = (float*)(ws + 6291456);           // 4*2048*128*4 = 4194304
  float* e1  = (float*)(ws + 10485760);          // 32768
  float* e2  = (float*)(ws + 10518528);          // 32768
  float* cm  = (float*)(ws + 10551296);          // 32768
  float* cs  = (float*)(ws + 10584064);          // 32768
  unsigned short* cat = (unsigned short*)(ws + 10616832);  // 2048*512*2 = 2097152
  unsigned short* owb = (unsigned short*)(ws + 12713984);  // VPAD*512*2 = 31326208
  float* ps  = (float*)(ws + 44040192);          // 2048*480*4 = 3932160
  float* lse = (float*)(ws + 47972352);          // 8192

  k_convert<<<2048, 256, 0, stream>>>(out_W, owb, (VOCAB * KDIM) / 4, (VPAD * KDIM) / 4);
  k_embed_ln<<<2048, 256, 0, stream>>>(tok, typ, tok_emb, type_emb, pos_emb, ln_g, ln_b, x);
  k_wh<<<256, 256, 0, stream>>>(x, W, Wh);
  k_e12<<<32, 256, 0, stream>>>(Wh, a, e1, e2);
  k_colstats<<<32, 256, 0, stream>>>(tok, typ, syn, hw, e1, e2, cm, cs);
  k_att<<<128, 256, 0, stream>>>(tok, typ, syn, hw, e1, e2, cm, cs, Wh, cat);
  k_gemm<<<16 * NTILE, 256, 0, stream>>>(cat, owb, out_b, (unsigned short*)out, ps);
  k_lse<<<2048, 256, 0, stream>>>(ps, lse);
  k_sub<<<2048, 1024, 0, stream>>>(out, lse);
}

// Round 6
// 393.369 us; speedup vs baseline: 1.4266x; 1.1372x over previous
//
#include <hip/hip_runtime.h>
#include <hip/hip_bf16.h>

#define VOCAB 30522
#define VPAD 30592   // VOCAB padded to multiple of 128 (for branch-free B staging)
#define HIDDEN 768
#define NHEADS 4
#define NHID 128
#define ROWS 2048
#define KDIM 512
#define LN_EPS 1e-12f
#define ALPHA_LR 0.01f
#define NEGV -9.0e15f
#define NTILE 239   // ceil(30522/128)
#define NT2 480     // padded partial count (2*NTILE=478, pad to 480)

typedef __attribute__((ext_vector_type(8))) short short8;
typedef __attribute__((ext_vector_type(4))) float floatx4;
typedef __attribute__((ext_vector_type(2))) float floatx2;
typedef __attribute__((ext_vector_type(4))) unsigned short ushort4v;

static __device__ __forceinline__ unsigned short f2bf(float f) {
  unsigned int u = __float_as_uint(f);
  unsigned int r = u + 0x7fffu + ((u >> 16) & 1u);
  return (unsigned short)(r >> 16);
}

// async global->LDS, 16B per lane (dest must be wave-linear: base + lane*16)
static __device__ __forceinline__ void gload16(const unsigned short* g, unsigned short* l) {
  __builtin_amdgcn_global_load_lds(
      (const __attribute__((address_space(1))) void*)g,
      (__attribute__((address_space(3))) void*)l, 16, 0, 0);
}

// ---------------- kernel 0: out_W fp32 -> bf16 (+ zero pad rows) ----------------
__global__ __launch_bounds__(256) void k_convert(const float* __restrict__ src,
                                                 unsigned short* __restrict__ dst,
                                                 int n4src, int n4tot) {
  int i = blockIdx.x * blockDim.x + threadIdx.x;
  int stride = gridDim.x * blockDim.x;
  for (; i < n4tot; i += stride) {
    ushort4v o = {0, 0, 0, 0};
    if (i < n4src) {
      floatx4 v = reinterpret_cast<const floatx4*>(src)[i];
      o.x = f2bf(v.x); o.y = f2bf(v.y); o.z = f2bf(v.z); o.w = f2bf(v.w);
    }
    reinterpret_cast<ushort4v*>(dst)[i] = o;
  }
}

// ---------------- kernel 0b: W (4,768,128) fp32 -> Wt (512,768) bf16 (transposed) ----------------
__global__ __launch_bounds__(256) void k_wt(const float* __restrict__ W, unsigned short* __restrict__ Wt) {
  int c = blockIdx.x;              // 0..511 = h*128 + f
  int h = c >> 7, f = c & 127;
  const float* src = W + (long)h * HIDDEN * NHID + f;   // stride NHID over d
  unsigned short* dst = Wt + (long)c * HIDDEN;
  for (int d = threadIdx.x; d < HIDDEN; d += 256)
    dst[d] = f2bf(src[(long)d * NHID]);
}

// ---------------- kernel 1: embeddings + LayerNorm (bf16 output) ----------------
__global__ __launch_bounds__(256) void k_embed_ln(const int* __restrict__ tok, const int* __restrict__ typ,
    const float* __restrict__ tok_emb, const float* __restrict__ type_emb, const float* __restrict__ pos_emb,
    const float* __restrict__ ln_g, const float* __restrict__ ln_b, unsigned short* __restrict__ xout) {
  int row = blockIdx.x;
  int n = row & 255;
  int t = tok[row], ty = typ[row];
  const float* te = tok_emb + (long)t * HIDDEN;
  const float* ye = type_emb + (long)ty * HIDDEN;
  const float* pe = pos_emb + (long)n * HIDDEN;
  float v[3]; float s = 0.f, ss = 0.f;
  #pragma unroll
  for (int q = 0; q < 3; q++) {
    int d = threadIdx.x + q * 256;
    float x = te[d] + ye[d] + pe[d];
    v[q] = x; s += x; ss += x * x;
  }
  __shared__ float red[8];
  for (int off = 32; off; off >>= 1) { s += __shfl_down(s, off); ss += __shfl_down(ss, off); }
  int wid = threadIdx.x >> 6;
  if ((threadIdx.x & 63) == 0) { red[wid] = s; red[4 + wid] = ss; }
  __syncthreads();
  if (threadIdx.x == 0) {
    float a = red[0] + red[1] + red[2] + red[3];
    float b = red[4] + red[5] + red[6] + red[7];
    float mu = a * (1.0f / 768.0f);
    float var = b * (1.0f / 768.0f) - mu * mu;
    red[0] = mu; red[1] = rsqrtf(var + LN_EPS);
  }
  __syncthreads();
  float mu = red[0], rstd = red[1];
  #pragma unroll
  for (int q = 0; q < 3; q++) {
    int d = threadIdx.x + q * 256;
    xout[(long)row * HIDDEN + d] = f2bf((v[q] - mu) * rstd * ln_g[d] + ln_b[d]);
  }
}

// ---------------- kernel 2: Wh = x @ W (bf16 MFMA, counted-vmcnt pipeline) ----------------
// A = xb (2048 x 768 bf16), B = Wt (512 x 768 bf16, row=output col); Wh fp32 [h][row][f]
__global__ __launch_bounds__(256) void k_wh(const unsigned short* __restrict__ A,
    const unsigned short* __restrict__ Bw, float* __restrict__ Wh) {
  int mt = blockIdx.x & 15, nt = blockIdx.x >> 4;   // 16 x 4
  int m0 = mt * 128, n0 = nt * 128;
  __shared__ __align__(16) unsigned short Al[2][128 * 64];
  __shared__ __align__(16) unsigned short Bl[2][128 * 64];
  int tid = threadIdx.x;
  int l = tid & 63, wid = tid >> 6;
  int wr = wid >> 1, wc = wid & 1;
  int lrow = l & 15, lgrp = l >> 4;
  floatx4 acc[4][4];
  #pragma unroll
  for (int i = 0; i < 4; i++)
    #pragma unroll
    for (int j = 0; j < 4; j++) acc[i][j] = (floatx4){0.f, 0.f, 0.f, 0.f};
  const unsigned short* Ab = A + (long)m0 * HIDDEN;
  const unsigned short* Bb = Bw + (long)n0 * HIDDEN;

  auto STAGE = [&](int t, int bufi) {
    #pragma unroll
    for (int q = 0; q < 4; q++) {
      int chunk = q * 256 + tid;
      int row = chunk >> 3, kp = chunk & 7, swz = kp ^ (row & 7);
      long off = (long)row * HIDDEN + t * 64 + swz * 8;
      gload16(Ab + off, &Al[bufi][chunk * 8]);
      gload16(Bb + off, &Bl[bufi][chunk * 8]);
    }
  };

  STAGE(0, 0);
  STAGE(1, 1);
  asm volatile("s_waitcnt vmcnt(8)" ::: "memory");
  __builtin_amdgcn_sched_barrier(0);
  __builtin_amdgcn_s_barrier();

  #pragma unroll
  for (int kt = 0; kt < 12; kt++) {
    int cur = kt & 1;
    short8 af[2][4], bf[2][4];
    #pragma unroll
    for (int kk = 0; kk < 2; kk++) {
      int sA = (kk * 4 + lgrp) ^ (lrow & 7);
      #pragma unroll
      for (int mi = 0; mi < 4; mi++)
        af[kk][mi] = *reinterpret_cast<const short8*>(&Al[cur][(wr * 64 + mi * 16 + lrow) * 64 + sA * 8]);
      #pragma unroll
      for (int ni = 0; ni < 4; ni++)
        bf[kk][ni] = *reinterpret_cast<const short8*>(&Bl[cur][(wc * 64 + ni * 16 + lrow) * 64 + sA * 8]);
    }
    asm volatile("s_waitcnt lgkmcnt(0)" ::: "memory");
    __builtin_amdgcn_sched_barrier(0);
    __builtin_amdgcn_s_barrier();
    __builtin_amdgcn_sched_barrier(0);
    if (kt < 10) STAGE(kt + 2, cur);
    #pragma unroll
    for (int kk = 0; kk < 2; kk++)
      #pragma unroll
      for (int mi = 0; mi < 4; mi++)
        #pragma unroll
        for (int ni = 0; ni < 4; ni++)
          acc[mi][ni] = __builtin_amdgcn_mfma_f32_16x16x32_bf16(af[kk][mi], bf[kk][ni], acc[mi][ni], 0, 0, 0);
    if (kt < 10) {
      asm volatile("s_waitcnt vmcnt(8)" ::: "memory");
    } else if (kt == 10) {
      asm volatile("s_waitcnt vmcnt(0)" ::: "memory");
    }
    __builtin_amdgcn_sched_barrier(0);
    if (kt < 11) __builtin_amdgcn_s_barrier();
  }

  #pragma unroll
  for (int mi = 0; mi < 4; mi++) {
    #pragma unroll
    for (int reg = 0; reg < 4; reg++) {
      int row = m0 + wr * 64 + mi * 16 + lgrp * 4 + reg;
      #pragma unroll
      for (int ni = 0; ni < 4; ni++) {
        int c = n0 + wc * 64 + ni * 16 + lrow;
        int h = c >> 7, f = c & 127;
        Wh[((long)h * ROWS + row) * NHID + f] = acc[mi][ni][reg];
      }
    }
  }
}

// ---------------- kernel 3: e1/e2 = Wh . a1/a2 ----------------
__global__ __launch_bounds__(256) void k_e12(const float* __restrict__ Wh, const float* __restrict__ a,
                                             float* __restrict__ e1, float* __restrict__ e2) {
  int h = blockIdx.x >> 3, b = blockIdx.x & 7;
  __shared__ float av[256];
  av[threadIdx.x] = a[h * 256 + threadIdx.x];
  __syncthreads();
  int row = b * 256 + threadIdx.x;
  const float* wr = Wh + ((long)h * ROWS + row) * NHID;
  float s1 = 0.f, s2 = 0.f;
  #pragma unroll 8
  for (int f = 0; f < 128; f++) { float w = wr[f]; s1 += w * av[f]; s2 += w * av[128 + f]; }
  e1[h * ROWS + row] = s1; e2[h * ROWS + row] = s2;
}

__device__ __forceinline__ unsigned char mk_flags(int t, int hwv, int tokv) {
  unsigned char fl = 0;
  if (hwv) {
    if (t == 1) fl |= 1;
    if (t == 3) fl |= 2;
    if (t == 0 || t == 2 || t == 5) fl |= 4;
    if (t == 6 || t == 4 || t == 0) fl |= 8;
  }
  if (tokv != 0) fl |= 16;
  return fl;
}

// ---------------- kernel 4a: column-wise softmax stats ----------------
__global__ __launch_bounds__(256) void k_colstats(const int* __restrict__ tok, const int* __restrict__ typ,
    const int* __restrict__ syn, const int* __restrict__ hw,
    const float* __restrict__ e1, const float* __restrict__ e2,
    float* __restrict__ colmax, float* __restrict__ colrs) {
  int h = blockIdx.x >> 3, b = blockIdx.x & 7;
  __shared__ float E1[256]; __shared__ int SY[256]; __shared__ unsigned char FL[256];
  int tid = threadIdx.x;
  int g = b * 256 + tid;
  FL[tid] = mk_flags(typ[g], hw[g], tok[g]);
  E1[tid] = e1[h * ROWS + g];
  SY[tid] = syn[g];
  __syncthreads();
  float e2j = e2[h * ROWS + g];
  int syj = SY[tid]; unsigned char flj = FL[tid];
  bool npj = flj & 16, d1j = flj & 4, d3j = flj & 8;
  float m = -INFINITY;
  for (int i = 0; i < 256; i++) {
    float e = E1[i] + e2j;
    e = e > 0.f ? e : ALPHA_LR * e;
    unsigned char fli = FL[i];
    bool vis = (SY[i] == syj) || ((fli & 1) && d1j) || ((fli & 2) && d3j);
    float v = (vis && npj) ? e : NEGV;
    m = fmaxf(m, v);
  }
  float s = 0.f;
  for (int i = 0; i < 256; i++) {
    float e = E1[i] + e2j;
    e = e > 0.f ? e : ALPHA_LR * e;
    unsigned char fli = FL[i];
    bool vis = (SY[i] == syj) || ((fli & 1) && d1j) || ((fli & 2) && d3j);
    float v = (vis && npj) ? e : NEGV;
    s += __expf(v - m);
  }
  int idx = (h * 8 + b) * 256 + tid;
  colmax[idx] = m;
  colrs[idx] = 1.0f / s;
}

// ---------------- kernel 4b: hp = elu(att @ Wh) -> cat (bf16) ----------------
// grid: 256 blocks = 8 row-chunks x (4 h x 8 b); each thread: 32 rows x 16 f
__global__ __launch_bounds__(256) void k_att(const int* __restrict__ tok, const int* __restrict__ typ,
    const int* __restrict__ syn, const int* __restrict__ hw,
    const float* __restrict__ e1, const float* __restrict__ e2,
    const float* __restrict__ colmax, const float* __restrict__ colrs,
    const float* __restrict__ Wh, unsigned short* __restrict__ cat) {
  int chunk = blockIdx.x & 7; int hb = blockIdx.x >> 3;
  int h = hb >> 3, b = hb & 7;
  __shared__ float E2[256], CM[256], CR[256];
  __shared__ int SY[256]; __shared__ unsigned char FL[256];
  __shared__ float WJ[64][128];
  int tid = threadIdx.x;
  {
    int g = b * 256 + tid;
    FL[tid] = mk_flags(typ[g], hw[g], tok[g]);
    E2[tid] = e2[h * ROWS + g];
    CM[tid] = colmax[hb * 256 + tid];
    CR[tid] = colrs[hb * 256 + tid];
    SY[tid] = syn[g];
  }
  __syncthreads();
  int i = chunk * 32 + (tid >> 3);
  int gi = b * 256 + i;
  float e1i = e1[h * ROWS + gi];
  unsigned char fli = FL[i];
  bool s1i = fli & 1, s3i = fli & 2;
  int syni = SY[i];
  int f0 = tid & 7;
  floatx4 acc4[4];
  #pragma unroll
  for (int k2 = 0; k2 < 4; k2++) acc4[k2] = (floatx4){0.f, 0.f, 0.f, 0.f};
  for (int j0 = 0; j0 < 256; j0 += 64) {
    #pragma unroll
    for (int q = 0; q < 8; q++) {
      int e = tid + q * 256;          // 0..2047
      int j = e >> 5, f4 = e & 31;
      *reinterpret_cast<floatx4*>(&WJ[j][f4 * 4]) =
          *reinterpret_cast<const floatx4*>(&Wh[((long)h * ROWS + b * 256 + j0 + j) * NHID + f4 * 4]);
    }
    __syncthreads();
    for (int j = 0; j < 64; j++) {
      int jj = j0 + j;
      unsigned char flj = FL[jj];
      bool vis = (syni == SY[jj]) || (s1i && (flj & 4)) || (s3i && (flj & 8));
      bool msk = vis && (flj & 16);
      float ev = e1i + E2[jj];
      ev = ev > 0.f ? ev : ALPHA_LR * ev;
      float v = msk ? ev : NEGV;
      float w = __expf(v - CM[jj]) * CR[jj];
      #pragma unroll
      for (int k2 = 0; k2 < 4; k2++) {
        floatx4 wv = *reinterpret_cast<const floatx4*>(&WJ[j][(f0 + 8 * k2) * 4]);
        acc4[k2] += wv * w;
      }
    }
    __syncthreads();
  }
  ushort4v* cr4 = reinterpret_cast<ushort4v*>(cat + (long)gi * KDIM + h * NHID);
  #pragma unroll
  for (int k2 = 0; k2 < 4; k2++) {
    ushort4v o4;
    #pragma unroll
    for (int e = 0; e < 4; e++) {
      float v = acc4[k2][e];
      v = v > 0.f ? v : __expf(v) - 1.f;
      o4[e] = f2bf(v);
    }
    cr4[f0 + 8 * k2] = o4;
  }
}

// ---------------- kernel 5: big GEMM (bf16 MFMA, counted-vmcnt pipeline) ----------------
__global__ __launch_bounds__(256) void k_gemm(const unsigned short* __restrict__ A,
    const unsigned short* __restrict__ Bw, const float* __restrict__ bias,
    unsigned short* __restrict__ otmp, float* __restrict__ ps) {
  // bijective XCD swizzle: 3824 blocks, 3824 % 8 == 0
  int bid = blockIdx.x;
  bid = (bid & 7) * ((16 * NTILE) >> 3) + (bid >> 3);
  int mt = bid & 15, nt = bid >> 4;
  int m0 = mt * 128, n0 = nt * 128;
  __shared__ __align__(16) unsigned short Al[2][128 * 64];
  __shared__ __align__(16) unsigned short Bl[2][128 * 64];
  int tid = threadIdx.x;
  int l = tid & 63, wid = tid >> 6;
  int wr = wid >> 1, wc = wid & 1;
  int lrow = l & 15, lgrp = l >> 4;
  floatx4 acc[4][4];
  #pragma unroll
  for (int i = 0; i < 4; i++)
    #pragma unroll
    for (int j = 0; j < 4; j++) acc[i][j] = (floatx4){0.f, 0.f, 0.f, 0.f};
  const unsigned short* Ab = A + (long)m0 * KDIM;
  const unsigned short* Bb = Bw + (long)n0 * KDIM;

  auto STAGE = [&](int t, int bufi) {
    #pragma unroll
    for (int q = 0; q < 4; q++) {
      int chunk = q * 256 + tid;
      int row = chunk >> 3, kp = chunk & 7, swz = kp ^ (row & 7);
      long off = (long)row * KDIM + t * 64 + swz * 8;
      gload16(Ab + off, &Al[bufi][chunk * 8]);
      gload16(Bb + off, &Bl[bufi][chunk * 8]);
    }
  };

  STAGE(0, 0);
  STAGE(1, 1);
  asm volatile("s_waitcnt vmcnt(8)" ::: "memory");
  __builtin_amdgcn_sched_barrier(0);
  __builtin_amdgcn_s_barrier();

  #pragma unroll
  for (int kt = 0; kt < 8; kt++) {
    int cur = kt & 1;
    short8 af[2][4], bf[2][4];
    #pragma unroll
    for (int kk = 0; kk < 2; kk++) {
      int sA = (kk * 4 + lgrp) ^ (lrow & 7);
      #pragma unroll
      for (int mi = 0; mi < 4; mi++)
        af[kk][mi] = *reinterpret_cast<const short8*>(&Al[cur][(wr * 64 + mi * 16 + lrow) * 64 + sA * 8]);
      #pragma unroll
      for (int ni = 0; ni < 4; ni++)
        bf[kk][ni] = *reinterpret_cast<const short8*>(&Bl[cur][(wc * 64 + ni * 16 + lrow) * 64 + sA * 8]);
    }
    asm volatile("s_waitcnt lgkmcnt(0)" ::: "memory");
    __builtin_amdgcn_sched_barrier(0);
    __builtin_amdgcn_s_barrier();
    __builtin_amdgcn_sched_barrier(0);
    if (kt < 6) STAGE(kt + 2, cur);
    #pragma unroll
    for (int kk = 0; kk < 2; kk++)
      #pragma unroll
      for (int mi = 0; mi < 4; mi++)
        #pragma unroll
        for (int ni = 0; ni < 4; ni++)
          acc[mi][ni] = __builtin_amdgcn_mfma_f32_16x16x32_bf16(af[kk][mi], bf[kk][ni], acc[mi][ni], 0, 0, 0);
    if (kt < 6) {
      asm volatile("s_waitcnt vmcnt(8)" ::: "memory");
    } else if (kt == 6) {
      asm volatile("s_waitcnt vmcnt(0)" ::: "memory");
    }
    __builtin_amdgcn_sched_barrier(0);
    if (kt < 7) __builtin_amdgcn_s_barrier();
  }

  // epilogue: bias + elu + bf16 store + per-row partial sum of exp (no max: logits are small)
  int t2 = nt * 2 + wc;
  float bcol[4]; bool valid[4]; int cols[4];
  #pragma unroll
  for (int ni = 0; ni < 4; ni++) {
    int c = n0 + wc * 64 + ni * 16 + lrow;
    cols[ni] = c; valid[ni] = c < VOCAB;
    bcol[ni] = valid[ni] ? bias[c] : 0.f;
  }
  #pragma unroll
  for (int mi = 0; mi < 4; mi++) {
    #pragma unroll
    for (int reg = 0; reg < 4; reg++) {
      int row = m0 + wr * 64 + mi * 16 + lgrp * 4 + reg;
      unsigned short* orow = otmp + (long)row * 2 * VOCAB;
      float se = 0.f;
      #pragma unroll
      for (int ni = 0; ni < 4; ni++) {
        float z = acc[mi][ni][reg] + bcol[ni];
        float o = z > 0.f ? z : __expf(z) - 1.f;
        if (valid[ni]) {
          orow[cols[ni]] = f2bf(o);
          se += __expf(o);
        }
      }
      #pragma unroll
      for (int off = 1; off < 16; off <<= 1) se += __shfl_xor(se, off);
      if (lrow == 0) ps[(long)row * NT2 + t2] = se;
    }
  }
}

// ---------------- kernel 6: reduce partial sumexp -> lse per row ----------------
__global__ __launch_bounds__(256) void k_lse(const float* __restrict__ ps, float* __restrict__ lse) {
  int row = blockIdx.x;
  int tid = threadIdx.x;
  const float* psr = ps + (long)row * NT2;
  float s = (tid < 478 ? psr[tid] : 0.f) + (tid + 256 < 478 ? psr[tid + 256] : 0.f);
  #pragma unroll
  for (int off = 32; off; off >>= 1) s += __shfl_xor(s, off);
  __shared__ float red[4];
  int wid = tid >> 6;
  if ((tid & 63) == 0) red[wid] = s;
  __syncthreads();
  if (tid == 0) lse[row] = logf(red[0] + red[1] + red[2] + red[3]);
}

// ---------------- kernel 7: in-place bf16 -> (fp32 - lse) row expansion ----------------
__global__ __launch_bounds__(1024) void k_sub(float* __restrict__ out, const float* __restrict__ lse) {
  int row = blockIdx.x;
  float L = lse[row];
  float* rb = out + (long)row * VOCAB;
  const unsigned int* src = reinterpret_cast<const unsigned int*>(rb);  // bf16 pairs
  int tid = threadIdx.x;
  unsigned int v[15];
  #pragma unroll
  for (int i = 0; i < 15; i++) {
    int p = tid + i * 1024;
    v[i] = (p < VOCAB / 2) ? src[p] : 0u;
  }
  __syncthreads();
  floatx2* dst = reinterpret_cast<floatx2*>(rb);
  #pragma unroll
  for (int i = 0; i < 15; i++) {
    int p = tid + i * 1024;
    if (p < VOCAB / 2) {
      unsigned int u = v[i];
      float lo = __uint_as_float((u & 0xffffu) << 16);
      float hi = __uint_as_float(u & 0xffff0000u);
      floatx2 o; o.x = lo - L; o.y = hi - L;
      dst[p] = o;
    }
  }
}

extern "C" void kernel_launch(void* const* d_in, const int* in_sizes, int n_in,
                              void* d_out, int out_size, void* d_ws, size_t ws_size,
                              hipStream_t stream) {
  const int* tok = (const int*)d_in[0];
  const int* typ = (const int*)d_in[1];
  const int* syn = (const int*)d_in[2];
  const int* hw  = (const int*)d_in[3];
  const float* tok_emb  = (const float*)d_in[4];
  const float* type_emb = (const float*)d_in[5];
  const float* pos_emb  = (const float*)d_in[6];
  const float* ln_g = (const float*)d_in[7];
  const float* ln_b = (const float*)d_in[8];
  const float* W    = (const float*)d_in[9];
  const float* a    = (const float*)d_in[10];
  const float* out_W = (const float*)d_in[11];
  const float* out_b = (const float*)d_in[12];
  float* out = (float*)d_out;
  char* ws = (char*)d_ws;
  // ws layout (bytes)
  unsigned short* xb = (unsigned short*)(ws + 0);          // 2048*768*2 = 3145728
  float* Wh  = (float*)(ws + 3145728);                     // 4*2048*128*4 = 4194304
  float* e1  = (float*)(ws + 7340032);                     // 32768
  float* e2  = (float*)(ws + 7372800);                     // 32768
  float* cm  = (float*)(ws + 7405568);                     // 32768
  float* cs  = (float*)(ws + 7438336);                     // 32768
  unsigned short* cat = (unsigned short*)(ws + 7471104);   // 2048*512*2 = 2097152
  unsigned short* Wt  = (unsigned short*)(ws + 9568256);   // 512*768*2 = 786432
  unsigned short* owb = (unsigned short*)(ws + 10354688);  // VPAD*512*2 = 31326208
  float* ps  = (float*)(ws + 41680896);                    // 2048*480*4 = 3932160
  float* lse = (float*)(ws + 45613056);                    // 8192

  k_convert<<<2048, 256, 0, stream>>>(out_W, owb, (VOCAB * KDIM) / 4, (VPAD * KDIM) / 4);
  k_wt<<<512, 256, 0, stream>>>(W, Wt);
  k_embed_ln<<<2048, 256, 0, stream>>>(tok, typ, tok_emb, type_emb, pos_emb, ln_g, ln_b, xb);
  k_wh<<<64, 256, 0, stream>>>(xb, Wt, Wh);
  k_e12<<<32, 256, 0, stream>>>(Wh, a, e1, e2);
  k_colstats<<<32, 256, 0, stream>>>(tok, typ, syn, hw, e1, e2, cm, cs);
  k_att<<<256, 256, 0, stream>>>(tok, typ, syn, hw, e1, e2, cm, cs, Wh, cat);
  k_gemm<<<16 * NTILE, 256, 0, stream>>>(cat, owb, out_b, (unsigned short*)out, ps);
  k_lse<<<2048, 256, 0, stream>>>(ps, lse);
  k_sub<<<2048, 1024, 0, stream>>>(out, lse);
}

// Round 7
// 360.351 us; speedup vs baseline: 1.5573x; 1.0916x over previous
//
#include <hip/hip_runtime.h>
#include <hip/hip_bf16.h>

#define VOCAB 30522
#define VPAD 30592   // VOCAB padded to multiple of 128 (for branch-free B staging)
#define HIDDEN 768
#define NHEADS 4
#define NHID 128
#define ROWS 2048
#define KDIM 512
#define LN_EPS 1e-12f
#define ALPHA_LR 0.01f
#define NEGV -9.0e15f
#define NTILE 239   // ceil(30522/128)

typedef __attribute__((ext_vector_type(8))) short short8;
typedef __attribute__((ext_vector_type(4))) float floatx4;
typedef __attribute__((ext_vector_type(2))) float floatx2;
typedef __attribute__((ext_vector_type(4))) unsigned short ushort4v;
typedef __attribute__((ext_vector_type(8))) unsigned short ushort8v;

static __device__ __forceinline__ unsigned short f2bf(float f) {
  unsigned int u = __float_as_uint(f);
  unsigned int r = u + 0x7fffu + ((u >> 16) & 1u);
  return (unsigned short)(r >> 16);
}

// async global->LDS, 16B per lane (dest must be wave-linear: base + lane*16)
static __device__ __forceinline__ void gload16(const unsigned short* g, unsigned short* l) {
  __builtin_amdgcn_global_load_lds(
      (const __attribute__((address_space(1))) void*)g,
      (__attribute__((address_space(3))) void*)l, 16, 0, 0);
}

// ---------------- kernel A: fused preprocessing ----------------
// blocks [0,2048):       out_W fp32 -> bf16 (+ zero pad rows)
// blocks [2048,2072):    W (4,768,128) -> Wt (512,768) bf16 transposed (LDS transpose)
// blocks [2072,4120):    embeddings + LayerNorm -> xb bf16
__global__ __launch_bounds__(256) void k_prep(const float* __restrict__ out_W,
    unsigned short* __restrict__ owb,
    const float* __restrict__ W, unsigned short* __restrict__ Wt,
    const int* __restrict__ tok, const int* __restrict__ typ,
    const float* __restrict__ tok_emb, const float* __restrict__ type_emb, const float* __restrict__ pos_emb,
    const float* __restrict__ ln_g, const float* __restrict__ ln_b, unsigned short* __restrict__ xout) {
  __shared__ unsigned short T[128][136];   // transpose staging (34.8 KB)
  __shared__ float red[8];
  int bid = blockIdx.x;
  if (bid < 2048) {
    // ---- convert out_W ----
    int n4src = (VOCAB * KDIM) / 4, n4tot = (VPAD * KDIM) / 4;
    int i = bid * 256 + threadIdx.x;
    int stride = 2048 * 256;
    for (; i < n4tot; i += stride) {
      ushort4v o = {0, 0, 0, 0};
      if (i < n4src) {
        floatx4 v = reinterpret_cast<const floatx4*>(out_W)[i];
        o.x = f2bf(v.x); o.y = f2bf(v.y); o.z = f2bf(v.z); o.w = f2bf(v.w);
      }
      reinterpret_cast<ushort4v*>(owb)[i] = o;
    }
  } else if (bid < 2072) {
    // ---- transpose W -> Wt ----
    int b = bid - 2048;
    int h = b & 3, dc = b >> 2;          // dc in 0..5 (6 chunks of 128 d)
    int tid = threadIdx.x;
    const float* Wb = W + ((long)h * HIDDEN + dc * 128) * NHID;
    #pragma unroll
    for (int q = 0; q < 16; q++) {
      int idx = q * 256 + tid;           // 0..4095 over 128d x 32 f4
      int d = idx >> 5, f4 = idx & 31;
      floatx4 v = *reinterpret_cast<const floatx4*>(&Wb[(long)d * NHID + f4 * 4]);
      #pragma unroll
      for (int j = 0; j < 4; j++) T[f4 * 4 + j][d] = f2bf(v[j]);
    }
    __syncthreads();
    int f = tid >> 1, rh = tid & 1;
    unsigned short* dst = Wt + (long)(h * 128 + f) * HIDDEN + dc * 128 + rh * 64;
    #pragma unroll
    for (int i = 0; i < 8; i++)
      *reinterpret_cast<ushort8v*>(&dst[i * 8]) =
          *reinterpret_cast<const ushort8v*>(&T[f][rh * 64 + i * 8]);
  } else {
    // ---- embeddings + LN ----
    int row = bid - 2072;
    int n = row & 255;
    int t = tok[row], ty = typ[row];
    const float* te = tok_emb + (long)t * HIDDEN;
    const float* ye = type_emb + (long)ty * HIDDEN;
    const float* pe = pos_emb + (long)n * HIDDEN;
    float v[3]; float s = 0.f, ss = 0.f;
    #pragma unroll
    for (int q = 0; q < 3; q++) {
      int d = threadIdx.x + q * 256;
      float x = te[d] + ye[d] + pe[d];
      v[q] = x; s += x; ss += x * x;
    }
    for (int off = 32; off; off >>= 1) { s += __shfl_down(s, off); ss += __shfl_down(ss, off); }
    int wid = threadIdx.x >> 6;
    if ((threadIdx.x & 63) == 0) { red[wid] = s; red[4 + wid] = ss; }
    __syncthreads();
    if (threadIdx.x == 0) {
      float a = red[0] + red[1] + red[2] + red[3];
      float b2 = red[4] + red[5] + red[6] + red[7];
      float mu = a * (1.0f / 768.0f);
      float var = b2 * (1.0f / 768.0f) - mu * mu;
      red[0] = mu; red[1] = rsqrtf(var + LN_EPS);
    }
    __syncthreads();
    float mu = red[0], rstd = red[1];
    #pragma unroll
    for (int q = 0; q < 3; q++) {
      int d = threadIdx.x + q * 256;
      xout[(long)row * HIDDEN + d] = f2bf((v[q] - mu) * rstd * ln_g[d] + ln_b[d]);
    }
  }
}

// ---------------- kernel 2: Wh = x @ W (bf16 MFMA, counted-vmcnt pipeline) ----------------
// A = xb (2048 x 768 bf16), B = Wt (512 x 768 bf16, row=output col); Wh fp32 [h][row][f]
__global__ __launch_bounds__(256) void k_wh(const unsigned short* __restrict__ A,
    const unsigned short* __restrict__ Bw, float* __restrict__ Wh) {
  int mt = blockIdx.x & 15, nt = blockIdx.x >> 4;   // 16 x 4
  int m0 = mt * 128, n0 = nt * 128;
  __shared__ __align__(16) unsigned short Al[2][128 * 64];
  __shared__ __align__(16) unsigned short Bl[2][128 * 64];
  int tid = threadIdx.x;
  int l = tid & 63, wid = tid >> 6;
  int wr = wid >> 1, wc = wid & 1;
  int lrow = l & 15, lgrp = l >> 4;
  floatx4 acc[4][4];
  #pragma unroll
  for (int i = 0; i < 4; i++)
    #pragma unroll
    for (int j = 0; j < 4; j++) acc[i][j] = (floatx4){0.f, 0.f, 0.f, 0.f};
  const unsigned short* Ab = A + (long)m0 * HIDDEN;
  const unsigned short* Bb = Bw + (long)n0 * HIDDEN;

  auto STAGE = [&](int t, int bufi) {
    #pragma unroll
    for (int q = 0; q < 4; q++) {
      int chunk = q * 256 + tid;
      int row = chunk >> 3, kp = chunk & 7, swz = kp ^ (row & 7);
      long off = (long)row * HIDDEN + t * 64 + swz * 8;
      gload16(Ab + off, &Al[bufi][chunk * 8]);
      gload16(Bb + off, &Bl[bufi][chunk * 8]);
    }
  };

  STAGE(0, 0);
  STAGE(1, 1);
  asm volatile("s_waitcnt vmcnt(8)" ::: "memory");
  __builtin_amdgcn_sched_barrier(0);
  __builtin_amdgcn_s_barrier();

  #pragma unroll
  for (int kt = 0; kt < 12; kt++) {
    int cur = kt & 1;
    short8 af[2][4], bf[2][4];
    #pragma unroll
    for (int kk = 0; kk < 2; kk++) {
      int sA = (kk * 4 + lgrp) ^ (lrow & 7);
      #pragma unroll
      for (int mi = 0; mi < 4; mi++)
        af[kk][mi] = *reinterpret_cast<const short8*>(&Al[cur][(wr * 64 + mi * 16 + lrow) * 64 + sA * 8]);
      #pragma unroll
      for (int ni = 0; ni < 4; ni++)
        bf[kk][ni] = *reinterpret_cast<const short8*>(&Bl[cur][(wc * 64 + ni * 16 + lrow) * 64 + sA * 8]);
    }
    asm volatile("s_waitcnt lgkmcnt(0)" ::: "memory");
    __builtin_amdgcn_sched_barrier(0);
    __builtin_amdgcn_s_barrier();
    __builtin_amdgcn_sched_barrier(0);
    if (kt < 10) STAGE(kt + 2, cur);
    #pragma unroll
    for (int kk = 0; kk < 2; kk++)
      #pragma unroll
      for (int mi = 0; mi < 4; mi++)
        #pragma unroll
        for (int ni = 0; ni < 4; ni++)
          acc[mi][ni] = __builtin_amdgcn_mfma_f32_16x16x32_bf16(af[kk][mi], bf[kk][ni], acc[mi][ni], 0, 0, 0);
    if (kt < 10) {
      asm volatile("s_waitcnt vmcnt(8)" ::: "memory");
    } else if (kt == 10) {
      asm volatile("s_waitcnt vmcnt(0)" ::: "memory");
    }
    __builtin_amdgcn_sched_barrier(0);
    if (kt < 11) __builtin_amdgcn_s_barrier();
  }

  #pragma unroll
  for (int mi = 0; mi < 4; mi++) {
    #pragma unroll
    for (int reg = 0; reg < 4; reg++) {
      int row = m0 + wr * 64 + mi * 16 + lgrp * 4 + reg;
      #pragma unroll
      for (int ni = 0; ni < 4; ni++) {
        int c = n0 + wc * 64 + ni * 16 + lrow;
        int h = c >> 7, f = c & 127;
        Wh[((long)h * ROWS + row) * NHID + f] = acc[mi][ni][reg];
      }
    }
  }
}

__device__ __forceinline__ unsigned char mk_flags(int t, int hwv, int tokv) {
  unsigned char fl = 0;
  if (hwv) {
    if (t == 1) fl |= 1;
    if (t == 3) fl |= 2;
    if (t == 0 || t == 2 || t == 5) fl |= 4;
    if (t == 6 || t == 4 || t == 0) fl |= 8;
  }
  if (tokv != 0) fl |= 16;
  return fl;
}

// ---------------- kernel 3: fused e1/e2 + column softmax stats ----------------
// grid 32 = (h,b); phase 1: e1/e2 dot products; phase 2: column max/sum
__global__ __launch_bounds__(256) void k_ecol(const int* __restrict__ tok, const int* __restrict__ typ,
    const int* __restrict__ syn, const int* __restrict__ hw,
    const float* __restrict__ Wh, const float* __restrict__ a,
    float* __restrict__ e1, float* __restrict__ e2,
    float* __restrict__ colmax, float* __restrict__ colrs) {
  int h = blockIdx.x >> 3, b = blockIdx.x & 7;
  __shared__ float av[256];
  __shared__ float E1[256]; __shared__ int SY[256]; __shared__ unsigned char FL[256];
  int tid = threadIdx.x;
  int g = b * 256 + tid;
  av[tid] = a[h * 256 + tid];
  FL[tid] = mk_flags(typ[g], hw[g], tok[g]);
  SY[tid] = syn[g];
  __syncthreads();
  // phase 1: e1/e2 for this block's rows
  const float* wr = Wh + ((long)h * ROWS + g) * NHID;
  float s1 = 0.f, s2 = 0.f;
  #pragma unroll 8
  for (int f = 0; f < 128; f++) { float w = wr[f]; s1 += w * av[f]; s2 += w * av[128 + f]; }
  e1[h * ROWS + g] = s1; e2[h * ROWS + g] = s2;
  E1[tid] = s1;
  __syncthreads();
  // phase 2: column stats (max over i, sum over i) for column j = tid
  float e2j = s2;
  int syj = SY[tid]; unsigned char flj = FL[tid];
  bool npj = flj & 16, d1j = flj & 4, d3j = flj & 8;
  float m = -INFINITY;
  for (int i = 0; i < 256; i++) {
    float e = E1[i] + e2j;
    e = e > 0.f ? e : ALPHA_LR * e;
    unsigned char fli = FL[i];
    bool vis = (SY[i] == syj) || ((fli & 1) && d1j) || ((fli & 2) && d3j);
    float v = (vis && npj) ? e : NEGV;
    m = fmaxf(m, v);
  }
  float s = 0.f;
  for (int i = 0; i < 256; i++) {
    float e = E1[i] + e2j;
    e = e > 0.f ? e : ALPHA_LR * e;
    unsigned char fli = FL[i];
    bool vis = (SY[i] == syj) || ((fli & 1) && d1j) || ((fli & 2) && d3j);
    float v = (vis && npj) ? e : NEGV;
    s += __expf(v - m);
  }
  int idx = (h * 8 + b) * 256 + tid;
  colmax[idx] = m;
  colrs[idx] = 1.0f / s;
}

// ---------------- kernel 4: hp = elu(att @ Wh) -> cat (bf16) ----------------
// grid: 256 blocks = 8 row-chunks x (4 h x 8 b); each thread: 32 rows x 16 f
__global__ __launch_bounds__(256) void k_att(const int* __restrict__ tok, const int* __restrict__ typ,
    const int* __restrict__ syn, const int* __restrict__ hw,
    const float* __restrict__ e1, const float* __restrict__ e2,
    const float* __restrict__ colmax, const float* __restrict__ colrs,
    const float* __restrict__ Wh, unsigned short* __restrict__ cat) {
  int chunk = blockIdx.x & 7; int hb = blockIdx.x >> 3;
  int h = hb >> 3, b = hb & 7;
  __shared__ float E2[256], CM[256], CR[256];
  __shared__ int SY[256]; __shared__ unsigned char FL[256];
  __shared__ float WJ[64][128];
  int tid = threadIdx.x;
  {
    int g = b * 256 + tid;
    FL[tid] = mk_flags(typ[g], hw[g], tok[g]);
    E2[tid] = e2[h * ROWS + g];
    CM[tid] = colmax[hb * 256 + tid];
    CR[tid] = colrs[hb * 256 + tid];
    SY[tid] = syn[g];
  }
  __syncthreads();
  int i = chunk * 32 + (tid >> 3);
  int gi = b * 256 + i;
  float e1i = e1[h * ROWS + gi];
  unsigned char fli = FL[i];
  bool s1i = fli & 1, s3i = fli & 2;
  int syni = SY[i];
  int f0 = tid & 7;
  floatx4 acc4[4];
  #pragma unroll
  for (int k2 = 0; k2 < 4; k2++) acc4[k2] = (floatx4){0.f, 0.f, 0.f, 0.f};
  for (int j0 = 0; j0 < 256; j0 += 64) {
    #pragma unroll
    for (int q = 0; q < 8; q++) {
      int e = tid + q * 256;          // 0..2047
      int j = e >> 5, f4 = e & 31;
      *reinterpret_cast<floatx4*>(&WJ[j][f4 * 4]) =
          *reinterpret_cast<const floatx4*>(&Wh[((long)h * ROWS + b * 256 + j0 + j) * NHID + f4 * 4]);
    }
    __syncthreads();
    for (int j = 0; j < 64; j++) {
      int jj = j0 + j;
      unsigned char flj = FL[jj];
      bool vis = (syni == SY[jj]) || (s1i && (flj & 4)) || (s3i && (flj & 8));
      bool msk = vis && (flj & 16);
      float ev = e1i + E2[jj];
      ev = ev > 0.f ? ev : ALPHA_LR * ev;
      float v = msk ? ev : NEGV;
      float w = __expf(v - CM[jj]) * CR[jj];
      #pragma unroll
      for (int k2 = 0; k2 < 4; k2++) {
        floatx4 wv = *reinterpret_cast<const floatx4*>(&WJ[j][(f0 + 8 * k2) * 4]);
        acc4[k2] += wv * w;
      }
    }
    __syncthreads();
  }
  ushort4v* cr4 = reinterpret_cast<ushort4v*>(cat + (long)gi * KDIM + h * NHID);
  #pragma unroll
  for (int k2 = 0; k2 < 4; k2++) {
    ushort4v o4;
    #pragma unroll
    for (int e = 0; e < 4; e++) {
      float v = acc4[k2][e];
      v = v > 0.f ? v : __expf(v) - 1.f;
      o4[e] = f2bf(v);
    }
    cr4[f0 + 8 * k2] = o4;
  }
}

// ---------------- kernel 5: big GEMM (bf16 MFMA, counted-vmcnt pipeline) ----------------
// writes bf16 elu'd logits into the first half of each output row's fp32 slot
__global__ __launch_bounds__(256) void k_gemm(const unsigned short* __restrict__ A,
    const unsigned short* __restrict__ Bw, const float* __restrict__ bias,
    unsigned short* __restrict__ otmp) {
  // bijective XCD swizzle: 3824 blocks, 3824 % 8 == 0
  int bid = blockIdx.x;
  bid = (bid & 7) * ((16 * NTILE) >> 3) + (bid >> 3);
  int mt = bid & 15, nt = bid >> 4;
  int m0 = mt * 128, n0 = nt * 128;
  __shared__ __align__(16) unsigned short Al[2][128 * 64];
  __shared__ __align__(16) unsigned short Bl[2][128 * 64];
  int tid = threadIdx.x;
  int l = tid & 63, wid = tid >> 6;
  int wr = wid >> 1, wc = wid & 1;
  int lrow = l & 15, lgrp = l >> 4;
  floatx4 acc[4][4];
  #pragma unroll
  for (int i = 0; i < 4; i++)
    #pragma unroll
    for (int j = 0; j < 4; j++) acc[i][j] = (floatx4){0.f, 0.f, 0.f, 0.f};
  const unsigned short* Ab = A + (long)m0 * KDIM;
  const unsigned short* Bb = Bw + (long)n0 * KDIM;

  auto STAGE = [&](int t, int bufi) {
    #pragma unroll
    for (int q = 0; q < 4; q++) {
      int chunk = q * 256 + tid;
      int row = chunk >> 3, kp = chunk & 7, swz = kp ^ (row & 7);
      long off = (long)row * KDIM + t * 64 + swz * 8;
      gload16(Ab + off, &Al[bufi][chunk * 8]);
      gload16(Bb + off, &Bl[bufi][chunk * 8]);
    }
  };

  STAGE(0, 0);
  STAGE(1, 1);
  asm volatile("s_waitcnt vmcnt(8)" ::: "memory");
  __builtin_amdgcn_sched_barrier(0);
  __builtin_amdgcn_s_barrier();

  #pragma unroll
  for (int kt = 0; kt < 8; kt++) {
    int cur = kt & 1;
    short8 af[2][4], bf[2][4];
    #pragma unroll
    for (int kk = 0; kk < 2; kk++) {
      int sA = (kk * 4 + lgrp) ^ (lrow & 7);
      #pragma unroll
      for (int mi = 0; mi < 4; mi++)
        af[kk][mi] = *reinterpret_cast<const short8*>(&Al[cur][(wr * 64 + mi * 16 + lrow) * 64 + sA * 8]);
      #pragma unroll
      for (int ni = 0; ni < 4; ni++)
        bf[kk][ni] = *reinterpret_cast<const short8*>(&Bl[cur][(wc * 64 + ni * 16 + lrow) * 64 + sA * 8]);
    }
    asm volatile("s_waitcnt lgkmcnt(0)" ::: "memory");
    __builtin_amdgcn_sched_barrier(0);
    __builtin_amdgcn_s_barrier();
    __builtin_amdgcn_sched_barrier(0);
    if (kt < 6) STAGE(kt + 2, cur);
    #pragma unroll
    for (int kk = 0; kk < 2; kk++)
      #pragma unroll
      for (int mi = 0; mi < 4; mi++)
        #pragma unroll
        for (int ni = 0; ni < 4; ni++)
          acc[mi][ni] = __builtin_amdgcn_mfma_f32_16x16x32_bf16(af[kk][mi], bf[kk][ni], acc[mi][ni], 0, 0, 0);
    if (kt < 6) {
      asm volatile("s_waitcnt vmcnt(8)" ::: "memory");
    } else if (kt == 6) {
      asm volatile("s_waitcnt vmcnt(0)" ::: "memory");
    }
    __builtin_amdgcn_sched_barrier(0);
    if (kt < 7) __builtin_amdgcn_s_barrier();
  }

  // epilogue: bias + elu + bf16 store only (lse handled downstream in k_sub)
  float bcol[4]; bool valid[4]; int cols[4];
  #pragma unroll
  for (int ni = 0; ni < 4; ni++) {
    int c = n0 + wc * 64 + ni * 16 + lrow;
    cols[ni] = c; valid[ni] = c < VOCAB;
    bcol[ni] = valid[ni] ? bias[c] : 0.f;
  }
  #pragma unroll
  for (int mi = 0; mi < 4; mi++) {
    #pragma unroll
    for (int reg = 0; reg < 4; reg++) {
      int row = m0 + wr * 64 + mi * 16 + lgrp * 4 + reg;
      unsigned short* orow = otmp + (long)row * 2 * VOCAB;
      #pragma unroll
      for (int ni = 0; ni < 4; ni++) {
        if (valid[ni]) {
          float z = acc[mi][ni][reg] + bcol[ni];
          float o = z > 0.f ? z : __expf(z) - 1.f;
          orow[cols[ni]] = f2bf(o);
        }
      }
    }
  }
}

// ---------------- kernel 6: in-place bf16 -> (fp32 - lse) with in-block lse ----------------
// one block per row: load packed bf16 row to registers, exp-sum + block reduce -> lse,
// then write fp32 (stores only after the reduction barrier, so in-place is safe).
__global__ __launch_bounds__(1024) void k_sub(float* __restrict__ out) {
  int row = blockIdx.x;
  float* rb = out + (long)row * VOCAB;
  const unsigned int* src = reinterpret_cast<const unsigned int*>(rb);  // bf16 pairs
  int tid = threadIdx.x;
  unsigned int v[15];
  float se = 0.f;
  #pragma unroll
  for (int i = 0; i < 15; i++) {
    int p = tid + i * 1024;
    v[i] = (p < VOCAB / 2) ? src[p] : 0u;
  }
  #pragma unroll
  for (int i = 0; i < 15; i++) {
    int p = tid + i * 1024;
    if (p < VOCAB / 2) {
      unsigned int u = v[i];
      float lo = __uint_as_float((u & 0xffffu) << 16);
      float hi = __uint_as_float(u & 0xffff0000u);
      se += __expf(lo) + __expf(hi);
    }
  }
  #pragma unroll
  for (int off = 32; off; off >>= 1) se += __shfl_xor(se, off);
  __shared__ float red[16];
  int wid = tid >> 6;
  if ((tid & 63) == 0) red[wid] = se;
  __syncthreads();
  if (tid < 16) {
    float r = red[tid];
    #pragma unroll
    for (int off = 8; off; off >>= 1) r += __shfl_xor(r, off);
    if (tid == 0) red[0] = logf(r);
  }
  __syncthreads();
  float L = red[0];
  floatx2* dst = reinterpret_cast<floatx2*>(rb);
  #pragma unroll
  for (int i = 0; i < 15; i++) {
    int p = tid + i * 1024;
    if (p < VOCAB / 2) {
      unsigned int u = v[i];
      float lo = __uint_as_float((u & 0xffffu) << 16);
      float hi = __uint_as_float(u & 0xffff0000u);
      floatx2 o; o.x = lo - L; o.y = hi - L;
      dst[p] = o;
    }
  }
}

extern "C" void kernel_launch(void* const* d_in, const int* in_sizes, int n_in,
                              void* d_out, int out_size, void* d_ws, size_t ws_size,
                              hipStream_t stream) {
  const int* tok = (const int*)d_in[0];
  const int* typ = (const int*)d_in[1];
  const int* syn = (const int*)d_in[2];
  const int* hw  = (const int*)d_in[3];
  const float* tok_emb  = (const float*)d_in[4];
  const float* type_emb = (const float*)d_in[5];
  const float* pos_emb  = (const float*)d_in[6];
  const float* ln_g = (const float*)d_in[7];
  const float* ln_b = (const float*)d_in[8];
  const float* W    = (const float*)d_in[9];
  const float* a    = (const float*)d_in[10];
  const float* out_W = (const float*)d_in[11];
  const float* out_b = (const float*)d_in[12];
  float* out = (float*)d_out;
  char* ws = (char*)d_ws;
  // ws layout (bytes)
  unsigned short* xb = (unsigned short*)(ws + 0);          // 2048*768*2 = 3145728
  float* Wh  = (float*)(ws + 3145728);                     // 4*2048*128*4 = 4194304
  float* e1  = (float*)(ws + 7340032);                     // 32768
  float* e2  = (float*)(ws + 7372800);                     // 32768
  float* cm  = (float*)(ws + 7405568);                     // 32768
  float* cs  = (float*)(ws + 7438336);                     // 32768
  unsigned short* cat = (unsigned short*)(ws + 7471104);   // 2048*512*2 = 2097152
  unsigned short* Wt  = (unsigned short*)(ws + 9568256);   // 512*768*2 = 786432
  unsigned short* owb = (unsigned short*)(ws + 10354688);  // VPAD*512*2 = 31326208

  k_prep<<<4120, 256, 0, stream>>>(out_W, owb, W, Wt, tok, typ,
                                   tok_emb, type_emb, pos_emb, ln_g, ln_b, xb);
  k_wh<<<64, 256, 0, stream>>>(xb, Wt, Wh);
  k_ecol<<<32, 256, 0, stream>>>(tok, typ, syn, hw, Wh, a, e1, e2, cm, cs);
  k_att<<<256, 256, 0, stream>>>(tok, typ, syn, hw, e1, e2, cm, cs, Wh, cat);
  k_gemm<<<16 * NTILE, 256, 0, stream>>>(cat, owb, out_b, (unsigned short*)out);
  k_sub<<<2048, 1024, 0, stream>>>(out);
}